// Round 1
// baseline (442.056 us; speedup 1.0000x reference)
//
#include <hip/hip_runtime.h>
#include <hip/hip_bf16.h>
#include <math.h>

// Problem: B=8, S=2048, D=512, U=512. fp32 in, fp32 out.
// d_out = context [8,2048,512] ++ attn [8,2048,2048]  (41,943,040 floats)
// Pipeline: X->bf16; W->Wt bf16; QKV = X@W (bf16 MFMA NT gemm);
// scores = Q@K^T * scale -> d_out attn region (fp32); softmax in-place;
// V^T transpose; context = attn@V via NT gemm (attn fp32->bf16 in staging).

typedef __attribute__((ext_vector_type(8))) short short8;
typedef __attribute__((ext_vector_type(4))) float fp32x4;

#define S_DIM 2048
#define D_DIM 512
#define U_DIM 512
#define BATCH 8

// RNE float->bf16 (finite inputs only)
__device__ __forceinline__ unsigned short f2bf(float f) {
    unsigned int u = __builtin_bit_cast(unsigned int, f);
    u += 0x7fffu + ((u >> 16) & 1u);
    return (unsigned short)(u >> 16);
}

// ---- staging helpers: copy 16 elements (one half-row of a 128x32 tile) ----
__device__ __forceinline__ void stage16(unsigned short* dst, const unsigned short* src) {
    *(short8*)(dst)     = *(const short8*)(src);
    *(short8*)(dst + 8) = *(const short8*)(src + 8);
}
__device__ __forceinline__ void stage16(unsigned short* dst, const float* src) {
#pragma unroll
    for (int c = 0; c < 16; c += 4) {
        float4 f = *(const float4*)(src + c);
        dst[c + 0] = f2bf(f.x);
        dst[c + 1] = f2bf(f.y);
        dst[c + 2] = f2bf(f.z);
        dst[c + 3] = f2bf(f.w);
    }
}

__device__ __forceinline__ void storeC(float* p, float v) { *p = v; }
__device__ __forceinline__ void storeC(unsigned short* p, float v) { *p = f2bf(v); }

// ---- NT GEMM: C[m][n] = scale * sum_k A[m][k] * B[n][k] ----
// A: [M,K] (bf16 ushort or fp32), B: [N,K] bf16, C: [M,N].
// 128x128 tile per block, 256 threads = 4 waves (2x2 of 64x64), BK=32.
template <typename AT, typename CT>
__global__ __launch_bounds__(256) void gemm_nt(
    const AT* __restrict__ A, const unsigned short* __restrict__ B, CT* __restrict__ C,
    int lda, int ldb, int ldc, int K,
    long aBatch, long bBatch, long cBatch, float scale) {
    const int tid = threadIdx.x;
    A += (long)blockIdx.z * aBatch;
    B += (long)blockIdx.z * bBatch;
    C += (long)blockIdx.z * cBatch;
    const int m0 = blockIdx.y * 128;
    const int n0 = blockIdx.x * 128;

    __shared__ unsigned short lsA[128 * 40];  // pad 32->40 to break bank strides
    __shared__ unsigned short lsB[128 * 40];

    const int wave = tid >> 6, lane = tid & 63;
    const int wm = (wave & 1) * 64;   // wave m-offset in tile
    const int wn = (wave >> 1) * 64;  // wave n-offset in tile
    const int lm = lane & 15;         // fragment row (m or n)
    const int quad = lane >> 4;       // k-group
    const int sr = tid >> 1;          // staging row 0..127
    const int sc = (tid & 1) * 16;    // staging col 0/16

    fp32x4 acc[4][4];
#pragma unroll
    for (int i = 0; i < 4; i++)
#pragma unroll
        for (int j = 0; j < 4; j++) acc[i][j] = {0.f, 0.f, 0.f, 0.f};

    for (int k0 = 0; k0 < K; k0 += 32) {
        __syncthreads();
        stage16(&lsA[sr * 40 + sc], A + (long)(m0 + sr) * lda + k0 + sc);
        stage16(&lsB[sr * 40 + sc], B + (long)(n0 + sr) * ldb + k0 + sc);
        __syncthreads();

        short8 af[4], bf[4];
#pragma unroll
        for (int i = 0; i < 4; i++)
            af[i] = *(const short8*)&lsA[(wm + i * 16 + lm) * 40 + quad * 8];
#pragma unroll
        for (int j = 0; j < 4; j++)
            bf[j] = *(const short8*)&lsB[(wn + j * 16 + lm) * 40 + quad * 8];
#pragma unroll
        for (int i = 0; i < 4; i++)
#pragma unroll
            for (int j = 0; j < 4; j++)
                acc[i][j] = __builtin_amdgcn_mfma_f32_16x16x32_bf16(af[i], bf[j], acc[i][j], 0, 0, 0);
    }

    // C/D layout: col = lane&15, row = quad*4 + reg
#pragma unroll
    for (int i = 0; i < 4; i++)
#pragma unroll
        for (int j = 0; j < 4; j++) {
            const int m = m0 + wm + i * 16 + quad * 4;
            const int n = n0 + wn + j * 16 + lm;
#pragma unroll
            for (int r = 0; r < 4; r++)
                storeC(&C[(long)(m + r) * ldc + n], acc[i][j][r] * scale);
        }
}

// ---- X fp32 -> bf16 (exact grid: 16384*512/4 float4s) ----
__global__ __launch_bounds__(256) void convert_x(const float* __restrict__ X,
                                                 unsigned short* __restrict__ Xb) {
    const int i = blockIdx.x * 256 + threadIdx.x;
    float4 f = ((const float4*)X)[i];
    unsigned int lo = ((unsigned int)f2bf(f.y) << 16) | f2bf(f.x);
    unsigned int hi = ((unsigned int)f2bf(f.w) << 16) | f2bf(f.z);
    ((uint2*)Xb)[i] = make_uint2(lo, hi);
}

// ---- W [D,U] fp32 -> Wt [U,D] bf16 ----
__global__ __launch_bounds__(256) void transpose_w(const float* __restrict__ W,
                                                   unsigned short* __restrict__ Wt) {
    __shared__ float t[32][33];
    const int tx = threadIdx.x & 31, ty = threadIdx.x >> 5;  // ty 0..7
    const int d0 = blockIdx.y * 32, u0 = blockIdx.x * 32;
#pragma unroll
    for (int i = 0; i < 32; i += 8) t[ty + i][tx] = W[(long)(d0 + ty + i) * U_DIM + u0 + tx];
    __syncthreads();
#pragma unroll
    for (int i = 0; i < 32; i += 8)
        Wt[(long)(u0 + ty + i) * D_DIM + d0 + tx] = f2bf(t[tx][ty + i]);
}

// ---- V [S,U] bf16 -> Vt [U,S] bf16, per batch ----
__global__ __launch_bounds__(256) void transpose_v(const unsigned short* __restrict__ V,
                                                   unsigned short* __restrict__ Vt) {
    V += (long)blockIdx.z * S_DIM * U_DIM;
    Vt += (long)blockIdx.z * U_DIM * S_DIM;
    __shared__ unsigned short t[32][33];
    const int tx = threadIdx.x & 31, ty = threadIdx.x >> 5;
    const int s0 = blockIdx.y * 32, u0 = blockIdx.x * 32;
#pragma unroll
    for (int i = 0; i < 32; i += 8) t[ty + i][tx] = V[(long)(s0 + ty + i) * U_DIM + u0 + tx];
    __syncthreads();
#pragma unroll
    for (int i = 0; i < 32; i += 8)
        Vt[(long)(u0 + ty + i) * S_DIM + s0 + tx] = t[tx][ty + i];
}

// ---- row softmax in place: 16384 rows x 2048 cols, one block per row ----
__global__ __launch_bounds__(256) void softmax_rows(float* __restrict__ attn) {
    float4* p = (float4*)(attn + (long)blockIdx.x * S_DIM);
    const int tid = threadIdx.x;
    const int lane = tid & 63, wave = tid >> 6;
    float4 a = p[tid];
    float4 b = p[tid + 256];

    float mx = fmaxf(fmaxf(fmaxf(a.x, a.y), fmaxf(a.z, a.w)),
                     fmaxf(fmaxf(b.x, b.y), fmaxf(b.z, b.w)));
#pragma unroll
    for (int off = 32; off > 0; off >>= 1) mx = fmaxf(mx, __shfl_down(mx, off));
    __shared__ float red[8];
    if (lane == 0) red[wave] = mx;
    __syncthreads();
    const float rowmax = fmaxf(fmaxf(red[0], red[1]), fmaxf(red[2], red[3]));

    a.x = __expf(a.x - rowmax); a.y = __expf(a.y - rowmax);
    a.z = __expf(a.z - rowmax); a.w = __expf(a.w - rowmax);
    b.x = __expf(b.x - rowmax); b.y = __expf(b.y - rowmax);
    b.z = __expf(b.z - rowmax); b.w = __expf(b.w - rowmax);
    float s = a.x + a.y + a.z + a.w + b.x + b.y + b.z + b.w;
#pragma unroll
    for (int off = 32; off > 0; off >>= 1) s += __shfl_down(s, off);
    if (lane == 0) red[4 + wave] = s;
    __syncthreads();
    const float inv = 1.0f / (red[4] + red[5] + red[6] + red[7]);

    a.x *= inv; a.y *= inv; a.z *= inv; a.w *= inv;
    b.x *= inv; b.y *= inv; b.z *= inv; b.w *= inv;
    p[tid] = a;
    p[tid + 256] = b;
}

extern "C" void kernel_launch(void* const* d_in, const int* in_sizes, int n_in,
                              void* d_out, int out_size, void* d_ws, size_t ws_size,
                              hipStream_t stream) {
    const float* X  = (const float*)d_in[0];
    const float* Wq = (const float*)d_in[1];
    const float* Wk = (const float*)d_in[2];
    const float* Wv = (const float*)d_in[3];

    float* ctx  = (float*)d_out;                                  // [8,2048,512]
    float* attn = (float*)d_out + (size_t)BATCH * S_DIM * U_DIM;  // [8,2048,2048]

    const size_t MTOT = (size_t)BATCH * S_DIM;  // 16384
    // Workspace layout (bf16/ushort). Vt aliases Xb (Xb dead after QKV gemm).
    unsigned short* Xb  = (unsigned short*)d_ws;          // 16384*512
    unsigned short* Wt  = Xb + MTOT * D_DIM;              // 3*512*512
    unsigned short* QKV = Wt + (size_t)3 * U_DIM * D_DIM; // 3*16384*512
    unsigned short* Vt  = Xb;                             // 8*512*2048 (alias)

    unsigned short* Q = QKV;
    unsigned short* Km = QKV + MTOT * U_DIM;
    unsigned short* V  = QKV + 2 * MTOT * U_DIM;

    // 1. converts / weight transposes
    convert_x<<<dim3((unsigned)(MTOT * D_DIM / 4 / 256)), 256, 0, stream>>>(X, Xb);
    transpose_w<<<dim3(16, 16), 256, 0, stream>>>(Wq, Wt);
    transpose_w<<<dim3(16, 16), 256, 0, stream>>>(Wk, Wt + (size_t)U_DIM * D_DIM);
    transpose_w<<<dim3(16, 16), 256, 0, stream>>>(Wv, Wt + (size_t)2 * U_DIM * D_DIM);

    // 2. QKV = X @ W  (z over {q,k,v}): M=16384, N=512, K=512
    gemm_nt<unsigned short, unsigned short><<<dim3(4, 128, 3), 256, 0, stream>>>(
        Xb, Wt, QKV, D_DIM, D_DIM, U_DIM, D_DIM,
        0L, (long)U_DIM * D_DIM, (long)MTOT * U_DIM, 1.0f);

    // 3. scores = Q @ K^T * 1/sqrt(U): per batch M=N=2048, K=512
    const float scale = 1.0f / sqrtf((float)U_DIM);
    gemm_nt<unsigned short, float><<<dim3(16, 16, BATCH), 256, 0, stream>>>(
        Q, Km, attn, U_DIM, U_DIM, S_DIM, U_DIM,
        (long)S_DIM * U_DIM, (long)S_DIM * U_DIM, (long)S_DIM * S_DIM, scale);

    // 4. softmax rows in place
    softmax_rows<<<dim3((unsigned)MTOT), 256, 0, stream>>>(attn);

    // 5. V^T per batch
    transpose_v<<<dim3(16, 64, BATCH), 256, 0, stream>>>(V, Vt);

    // 6. context = attn @ V: per batch M=2048, N=512, K=2048
    gemm_nt<float, float><<<dim3(4, 16, BATCH), 256, 0, stream>>>(
        attn, Vt, ctx, S_DIM, S_DIM, U_DIM, S_DIM,
        (long)S_DIM * S_DIM, (long)U_DIM * S_DIM, (long)S_DIM * U_DIM, 1.0f);
}

// Round 2
// 390.088 us; speedup vs baseline: 1.1332x; 1.1332x over previous
//
#include <hip/hip_runtime.h>
#include <hip/hip_bf16.h>
#include <math.h>

// B=8, S=2048, D=512, U=512. fp32 in, fp32 out.
// d_out = context [8,2048,512] ++ attn [8,2048,2048]
// Round 2: global_load_lds (width=16) async staging in all GEMMs (m97 lever),
// softmax dual-writes bf16 attn so the context GEMM reads bf16 A directly.

typedef __attribute__((ext_vector_type(8))) short short8;
typedef __attribute__((ext_vector_type(4))) float fp32x4;

#define S_DIM 2048
#define D_DIM 512
#define U_DIM 512
#define BATCH 8

#define GLOBAL_AS __attribute__((address_space(1)))
#define LDS_AS __attribute__((address_space(3)))

// RNE float->bf16 (finite inputs only)
__device__ __forceinline__ unsigned short f2bf(float f) {
    unsigned int u = __builtin_bit_cast(unsigned int, f);
    u += 0x7fffu + ((u >> 16) & 1u);
    return (unsigned short)(u >> 16);
}
__device__ __forceinline__ unsigned int pack2bf(float lo, float hi) {
    return ((unsigned int)f2bf(hi) << 16) | f2bf(lo);
}

// async global->LDS, 16 B per lane; LDS dest = wave-uniform base + lane*16
__device__ __forceinline__ void async_copy16(const unsigned short* g, unsigned short* l) {
    __builtin_amdgcn_global_load_lds((const GLOBAL_AS unsigned int*)(const void*)g,
                                     (LDS_AS unsigned int*)(void*)l, 16, 0, 0);
}

__device__ __forceinline__ void storeC(float* p, float v) { *p = v; }
__device__ __forceinline__ void storeC(unsigned short* p, float v) { *p = f2bf(v); }

// ---- fast NT GEMM (m97-style): C[m][n] = scale * sum_k A[m][k]*B[n][k] ----
// A,B bf16; 128x128 tile, 4 waves (2x2 of 64x64), BK=32, async LDS staging.
template <typename CT>
__global__ __launch_bounds__(256) void gemm_nt_async(
    const unsigned short* __restrict__ A, const unsigned short* __restrict__ B,
    CT* __restrict__ C, int lda, int ldb, int ldc, int K,
    long aBatch, long bBatch, long cBatch, float scale) {
    const int tid = threadIdx.x;
    A += (long)blockIdx.z * aBatch;
    B += (long)blockIdx.z * bBatch;
    C += (long)blockIdx.z * cBatch;
    const int m0 = blockIdx.y * 128;
    const int n0 = blockIdx.x * 128;

    // UNPADDED [128][32] bf16 (8 KB each): global_load_lds needs contiguous
    // lane order; b128 fragment reads at 64 B row stride sit at the wave64
    // LDS floor (8 clk) anyway.
    __shared__ unsigned short lsA[128 * 32];
    __shared__ unsigned short lsB[128 * 32];

    const int wave = tid >> 6, lane = tid & 63;
    const int wm = (wave & 1) * 64;
    const int wn = (wave >> 1) * 64;
    const int lm = lane & 15;
    const int quad = lane >> 4;

    // staging: wave w covers rows [w*32, w*32+32), lane l -> row w*32+l/4,
    // col (l&3)*8 (8 bf16 = 16 B). Two instructions per operand (rows +0,+16).
    const int srow = wave * 32 + (lane >> 2);
    const int scol = (lane & 3) * 8;
    const unsigned short* aPtr = A + (long)(m0 + srow) * lda + scol;
    const unsigned short* bPtr = B + (long)(n0 + srow) * ldb + scol;
    unsigned short* aDst0 = &lsA[wave * 1024];        // wave-uniform bases
    unsigned short* aDst1 = &lsA[wave * 1024 + 512];
    unsigned short* bDst0 = &lsB[wave * 1024];
    unsigned short* bDst1 = &lsB[wave * 1024 + 512];

    fp32x4 acc[4][4];
#pragma unroll
    for (int i = 0; i < 4; i++)
#pragma unroll
        for (int j = 0; j < 4; j++) acc[i][j] = {0.f, 0.f, 0.f, 0.f};

    for (int k0 = 0; k0 < K; k0 += 32) {
        __syncthreads();  // previous compute done before overwrite
        async_copy16(aPtr, aDst0);
        async_copy16(aPtr + 16 * (long)lda, aDst1);
        async_copy16(bPtr, bDst0);
        async_copy16(bPtr + 16 * (long)ldb, bDst1);
        aPtr += 32;
        bPtr += 32;
        __syncthreads();  // compiler emits vmcnt(0) drain before barrier

        short8 af[4], bf[4];
#pragma unroll
        for (int i = 0; i < 4; i++)
            af[i] = *(const short8*)&lsA[(wm + i * 16 + lm) * 32 + quad * 8];
#pragma unroll
        for (int j = 0; j < 4; j++)
            bf[j] = *(const short8*)&lsB[(wn + j * 16 + lm) * 32 + quad * 8];
#pragma unroll
        for (int i = 0; i < 4; i++)
#pragma unroll
            for (int j = 0; j < 4; j++)
                acc[i][j] = __builtin_amdgcn_mfma_f32_16x16x32_bf16(af[i], bf[j], acc[i][j], 0, 0, 0);
    }

    // C/D layout: col = lane&15, row = quad*4 + reg
#pragma unroll
    for (int i = 0; i < 4; i++)
#pragma unroll
        for (int j = 0; j < 4; j++) {
            const int m = m0 + wm + i * 16 + quad * 4;
            const int n = n0 + wn + j * 16 + lm;
#pragma unroll
            for (int r = 0; r < 4; r++)
                storeC(&C[(long)(m + r) * ldc + n], acc[i][j][r] * scale);
        }
}

// ---- fallback NT GEMM (round-1 style, synchronous staging, fp32 A ok) ----
__device__ __forceinline__ void stage16(unsigned short* dst, const unsigned short* src) {
    *(short8*)(dst)     = *(const short8*)(src);
    *(short8*)(dst + 8) = *(const short8*)(src + 8);
}
__device__ __forceinline__ void stage16(unsigned short* dst, const float* src) {
#pragma unroll
    for (int c = 0; c < 16; c += 4) {
        float4 f = *(const float4*)(src + c);
        dst[c + 0] = f2bf(f.x);
        dst[c + 1] = f2bf(f.y);
        dst[c + 2] = f2bf(f.z);
        dst[c + 3] = f2bf(f.w);
    }
}
template <typename AT, typename CT>
__global__ __launch_bounds__(256) void gemm_nt(
    const AT* __restrict__ A, const unsigned short* __restrict__ B, CT* __restrict__ C,
    int lda, int ldb, int ldc, int K,
    long aBatch, long bBatch, long cBatch, float scale) {
    const int tid = threadIdx.x;
    A += (long)blockIdx.z * aBatch;
    B += (long)blockIdx.z * bBatch;
    C += (long)blockIdx.z * cBatch;
    const int m0 = blockIdx.y * 128;
    const int n0 = blockIdx.x * 128;

    __shared__ unsigned short lsA[128 * 40];
    __shared__ unsigned short lsB[128 * 40];

    const int wave = tid >> 6, lane = tid & 63;
    const int wm = (wave & 1) * 64;
    const int wn = (wave >> 1) * 64;
    const int lm = lane & 15;
    const int quad = lane >> 4;
    const int sr = tid >> 1;
    const int sc = (tid & 1) * 16;

    fp32x4 acc[4][4];
#pragma unroll
    for (int i = 0; i < 4; i++)
#pragma unroll
        for (int j = 0; j < 4; j++) acc[i][j] = {0.f, 0.f, 0.f, 0.f};

    for (int k0 = 0; k0 < K; k0 += 32) {
        __syncthreads();
        stage16(&lsA[sr * 40 + sc], A + (long)(m0 + sr) * lda + k0 + sc);
        stage16(&lsB[sr * 40 + sc], B + (long)(n0 + sr) * ldb + k0 + sc);
        __syncthreads();

        short8 af[4], bf[4];
#pragma unroll
        for (int i = 0; i < 4; i++)
            af[i] = *(const short8*)&lsA[(wm + i * 16 + lm) * 40 + quad * 8];
#pragma unroll
        for (int j = 0; j < 4; j++)
            bf[j] = *(const short8*)&lsB[(wn + j * 16 + lm) * 40 + quad * 8];
#pragma unroll
        for (int i = 0; i < 4; i++)
#pragma unroll
            for (int j = 0; j < 4; j++)
                acc[i][j] = __builtin_amdgcn_mfma_f32_16x16x32_bf16(af[i], bf[j], acc[i][j], 0, 0, 0);
    }
#pragma unroll
    for (int i = 0; i < 4; i++)
#pragma unroll
        for (int j = 0; j < 4; j++) {
            const int m = m0 + wm + i * 16 + quad * 4;
            const int n = n0 + wn + j * 16 + lm;
#pragma unroll
            for (int r = 0; r < 4; r++)
                storeC(&C[(long)(m + r) * ldc + n], acc[i][j][r] * scale);
        }
}

// ---- X fp32 -> bf16 ----
__global__ __launch_bounds__(256) void convert_x(const float* __restrict__ X,
                                                 unsigned short* __restrict__ Xb) {
    const int i = blockIdx.x * 256 + threadIdx.x;
    float4 f = ((const float4*)X)[i];
    ((uint2*)Xb)[i] = make_uint2(pack2bf(f.x, f.y), pack2bf(f.z, f.w));
}

// ---- W [D,U] fp32 -> Wt [U,D] bf16 ----
__global__ __launch_bounds__(256) void transpose_w(const float* __restrict__ W,
                                                   unsigned short* __restrict__ Wt) {
    __shared__ float t[32][33];
    const int tx = threadIdx.x & 31, ty = threadIdx.x >> 5;
    const int d0 = blockIdx.y * 32, u0 = blockIdx.x * 32;
#pragma unroll
    for (int i = 0; i < 32; i += 8) t[ty + i][tx] = W[(long)(d0 + ty + i) * U_DIM + u0 + tx];
    __syncthreads();
#pragma unroll
    for (int i = 0; i < 32; i += 8)
        Wt[(long)(u0 + ty + i) * D_DIM + d0 + tx] = f2bf(t[tx][ty + i]);
}

// ---- V [S,U] bf16 -> Vt [U,S] bf16, per batch ----
__global__ __launch_bounds__(256) void transpose_v(const unsigned short* __restrict__ V,
                                                   unsigned short* __restrict__ Vt) {
    V += (long)blockIdx.z * S_DIM * U_DIM;
    Vt += (long)blockIdx.z * U_DIM * S_DIM;
    __shared__ unsigned short t[32][33];
    const int tx = threadIdx.x & 31, ty = threadIdx.x >> 5;
    const int s0 = blockIdx.y * 32, u0 = blockIdx.x * 32;
#pragma unroll
    for (int i = 0; i < 32; i += 8) t[ty + i][tx] = V[(long)(s0 + ty + i) * U_DIM + u0 + tx];
    __syncthreads();
#pragma unroll
    for (int i = 0; i < 32; i += 8)
        Vt[(long)(u0 + ty + i) * S_DIM + s0 + tx] = t[tx][ty + i];
}

// ---- row softmax in place + optional bf16 sidecar ----
__global__ __launch_bounds__(256) void softmax_rows(float* __restrict__ attn,
                                                    unsigned short* __restrict__ attn_bf) {
    float4* p = (float4*)(attn + (long)blockIdx.x * S_DIM);
    const int tid = threadIdx.x;
    const int lane = tid & 63, wave = tid >> 6;
    float4 a = p[tid];
    float4 b = p[tid + 256];

    float mx = fmaxf(fmaxf(fmaxf(a.x, a.y), fmaxf(a.z, a.w)),
                     fmaxf(fmaxf(b.x, b.y), fmaxf(b.z, b.w)));
#pragma unroll
    for (int off = 32; off > 0; off >>= 1) mx = fmaxf(mx, __shfl_down(mx, off));
    __shared__ float red[8];
    if (lane == 0) red[wave] = mx;
    __syncthreads();
    const float rowmax = fmaxf(fmaxf(red[0], red[1]), fmaxf(red[2], red[3]));

    a.x = __expf(a.x - rowmax); a.y = __expf(a.y - rowmax);
    a.z = __expf(a.z - rowmax); a.w = __expf(a.w - rowmax);
    b.x = __expf(b.x - rowmax); b.y = __expf(b.y - rowmax);
    b.z = __expf(b.z - rowmax); b.w = __expf(b.w - rowmax);
    float s = a.x + a.y + a.z + a.w + b.x + b.y + b.z + b.w;
#pragma unroll
    for (int off = 32; off > 0; off >>= 1) s += __shfl_down(s, off);
    if (lane == 0) red[4 + wave] = s;
    __syncthreads();
    const float inv = 1.0f / (red[4] + red[5] + red[6] + red[7]);

    a.x *= inv; a.y *= inv; a.z *= inv; a.w *= inv;
    b.x *= inv; b.y *= inv; b.z *= inv; b.w *= inv;
    p[tid] = a;
    p[tid + 256] = b;

    if (attn_bf) {
        uint2* q = (uint2*)(attn_bf + (long)blockIdx.x * S_DIM);
        q[tid]       = make_uint2(pack2bf(a.x, a.y), pack2bf(a.z, a.w));
        q[tid + 256] = make_uint2(pack2bf(b.x, b.y), pack2bf(b.z, b.w));
    }
}

extern "C" void kernel_launch(void* const* d_in, const int* in_sizes, int n_in,
                              void* d_out, int out_size, void* d_ws, size_t ws_size,
                              hipStream_t stream) {
    const float* X  = (const float*)d_in[0];
    const float* Wq = (const float*)d_in[1];
    const float* Wk = (const float*)d_in[2];
    const float* Wv = (const float*)d_in[3];

    float* ctx  = (float*)d_out;
    float* attn = (float*)d_out + (size_t)BATCH * S_DIM * U_DIM;

    const size_t MTOT = (size_t)BATCH * S_DIM;  // 16384
    // ws layout (ushort elems): Xb | Wt | QKV ; Vt aliases Xb (dead after QKV
    // gemm); attn_bf aliases QKV (dead after transpose_v), extends 16.8 MB past.
    unsigned short* Xb  = (unsigned short*)d_ws;          // 16 MB
    unsigned short* Wt  = Xb + MTOT * D_DIM;              // 1.5 MB
    unsigned short* QKV = Wt + (size_t)3 * U_DIM * D_DIM; // 48 MB
    unsigned short* Vt  = Xb;
    unsigned short* attn_bf = QKV;                        // 64 MB (aliases QKV)

    unsigned short* Q  = QKV;
    unsigned short* Km = QKV + MTOT * U_DIM;
    unsigned short* V  = QKV + 2 * MTOT * U_DIM;

    // peak ws need with bf16-attn sidecar: Xb + Wt + attn_bf
    const size_t need = (MTOT * D_DIM + (size_t)3 * U_DIM * D_DIM) * 2 +
                        (size_t)BATCH * S_DIM * S_DIM * 2;
    const bool fast = ws_size >= need;

    convert_x<<<dim3((unsigned)(MTOT * D_DIM / 4 / 256)), 256, 0, stream>>>(X, Xb);
    transpose_w<<<dim3(16, 16), 256, 0, stream>>>(Wq, Wt);
    transpose_w<<<dim3(16, 16), 256, 0, stream>>>(Wk, Wt + (size_t)U_DIM * D_DIM);
    transpose_w<<<dim3(16, 16), 256, 0, stream>>>(Wv, Wt + (size_t)2 * U_DIM * D_DIM);

    // QKV = X @ W: M=16384, N=512, K=512 (z over {q,k,v})
    gemm_nt_async<unsigned short><<<dim3(4, 128, 3), 256, 0, stream>>>(
        Xb, Wt, QKV, D_DIM, D_DIM, U_DIM, D_DIM,
        0L, (long)U_DIM * D_DIM, (long)MTOT * U_DIM, 1.0f);

    // scores = Q @ K^T * 1/sqrt(U): per batch M=N=2048, K=512
    const float scale = 1.0f / sqrtf((float)U_DIM);
    gemm_nt_async<float><<<dim3(16, 16, BATCH), 256, 0, stream>>>(
        Q, Km, attn, U_DIM, U_DIM, S_DIM, U_DIM,
        (long)S_DIM * U_DIM, (long)S_DIM * U_DIM, (long)S_DIM * S_DIM, scale);

    // V^T per batch (must precede softmax's attn_bf write over QKV region)
    transpose_v<<<dim3(16, 64, BATCH), 256, 0, stream>>>(V, Vt);

    // softmax in place (+ bf16 sidecar when ws permits)
    softmax_rows<<<dim3((unsigned)MTOT), 256, 0, stream>>>(attn, fast ? attn_bf : nullptr);

    // context = attn @ V: per batch M=2048, N=512, K=2048
    if (fast) {
        gemm_nt_async<float><<<dim3(4, 16, BATCH), 256, 0, stream>>>(
            attn_bf, Vt, ctx, S_DIM, S_DIM, U_DIM, S_DIM,
            (long)S_DIM * S_DIM, (long)U_DIM * S_DIM, (long)S_DIM * U_DIM, 1.0f);
    } else {
        gemm_nt<float, float><<<dim3(4, 16, BATCH), 256, 0, stream>>>(
            attn, Vt, ctx, S_DIM, S_DIM, U_DIM, S_DIM,
            (long)S_DIM * S_DIM, (long)U_DIM * S_DIM, (long)S_DIM * U_DIM, 1.0f);
    }
}